// Round 3
// baseline (113.785 us; speedup 1.0000x reference)
//
#include <hip/hip_runtime.h>

// PlatonicConv: G=12, H_EFF=2, HEAD_D=16, GH=24, N=2048 (32 graphs x 64 nodes),
// IN_C=EMB=OUT_C=384. Fully-connected edges per graph => dense attention S=64,D=16
// per (graph, group-head). f32 in/out; bf16 MFMA inside.
//
// R3 pipeline (3 kernels):
//   K0 prep: W{q,k,v,o} -> bf16 WT[1536][384] (transposed), x -> bf16 xb
//   K1 fused: per (graph, gh) block: QKV slice GEMM (direct-global MFMA frags,
//             no LDS/barriers) + bias + RoPE + dense attention -> attn bf16
//   K2 out-proj: 1-wave blocks, 16x64 tiles, direct-global frags, no barriers

#define NNODES   2048
#define KDIM     384
#define NGRAPHS  32
#define NPG      64
#define GHEADS   24
#define HDIM     16

typedef __attribute__((ext_vector_type(8))) short short8;
typedef __attribute__((ext_vector_type(4))) float f32x4;

__device__ __forceinline__ short f2bf(float f) {
    unsigned u = __builtin_bit_cast(unsigned, f);
    u += 0x7FFFu + ((u >> 16) & 1u);     // RTNE to bf16
    return (short)(u >> 16);
}

// ---- K0: weight transpose+convert, x convert ------------------------------
__global__ __launch_bounds__(256) void prep_kernel(
    const float* __restrict__ x,
    const float* __restrict__ Wq, const float* __restrict__ Wk,
    const float* __restrict__ Wv, const float* __restrict__ Wo,
    short* __restrict__ WT, short* __restrict__ xb)
{
    const int b   = blockIdx.x;
    const int tid = threadIdx.x;
    if (b < 576) {
        // transpose one 32x32 tile of one weight matrix: WT[n][k] = W[k][n]
        __shared__ float tile[32][33];
        const int mat = b / 144;
        const int t   = b - mat * 144;
        const int k0  = (t / 12) * 32;
        const int n0  = (t % 12) * 32;
        const float* W = (mat == 0) ? Wq : (mat == 1) ? Wk : (mat == 2) ? Wv : Wo;
        const int cx = tid & 31;
        const int ty = tid >> 5;
        #pragma unroll
        for (int i = 0; i < 4; ++i) {
            const int rr = ty + 8 * i;
            tile[rr][cx] = W[(size_t)(k0 + rr) * KDIM + n0 + cx];
        }
        __syncthreads();
        #pragma unroll
        for (int i = 0; i < 4; ++i) {
            const int rr = ty + 8 * i;
            WT[(size_t)(mat * 384 + n0 + rr) * KDIM + k0 + cx] = f2bf(tile[cx][rr]);
        }
    } else {
        // x f32 -> bf16, 8 elems/thread
        const int idx = ((b - 576) * 256 + tid) * 8;
        const f32x4* xp = reinterpret_cast<const f32x4*>(x + idx);
        f32x4 v0 = xp[0], v1 = xp[1];
        short8 o;
        o[0] = f2bf(v0[0]); o[1] = f2bf(v0[1]); o[2] = f2bf(v0[2]); o[3] = f2bf(v0[3]);
        o[4] = f2bf(v1[0]); o[5] = f2bf(v1[1]); o[6] = f2bf(v1[2]); o[7] = f2bf(v1[3]);
        *reinterpret_cast<short8*>(xb + idx) = o;
    }
}

// ---- K1: fused QKV-slice GEMM + RoPE + attention --------------------------
// Block = (graph gr, group-head gh). 4 waves; wave w owns node rows w*16..+16.
// GEMM phase: acc[t] (t=0 q, 1 k, 2 v) 16x16 tiles, K=384, operands direct
// from global (L1/L2-resident). Then bias+RoPE in-register, publish to LDS,
// one barrier, per-wave attention (lane = (qrow, kquad)), shfl reductions.
__global__ __launch_bounds__(256) void qkv_attn_kernel(
    const short* __restrict__ xb,     // [2048][384] bf16
    const short* __restrict__ WT,     // [1536][384] bf16 (q|k|v|o cols as rows)
    const float* __restrict__ bq, const float* __restrict__ bk,
    const float* __restrict__ bv,
    const float* __restrict__ pos, const float* __restrict__ freqs,
    short* __restrict__ attn_out)     // [2048][384] bf16
{
    const int blk  = blockIdx.x;
    const int gr   = blk / GHEADS;
    const int gh   = blk - gr * GHEADS;
    const int tid  = threadIdx.x;
    const int w    = tid >> 6;
    const int lane = tid & 63;
    const int fr   = lane & 15;
    const int hi   = lane >> 4;

    // ---------- GEMM phase ----------
    const short* aP  = xb + (size_t)(gr * 64 + w * 16 + fr) * KDIM + hi * 8;
    const short* bqP = WT + (size_t)(gh * 16 + fr) * KDIM + hi * 8;
    const short* bkP = bqP + (size_t)384 * KDIM;
    const short* bvP = bkP + (size_t)384 * KDIM;

    f32x4 acc[3];
    acc[0] = (f32x4){0.f, 0.f, 0.f, 0.f};
    acc[1] = acc[0];
    acc[2] = acc[0];

    #pragma unroll 4
    for (int kt = 0; kt < KDIM; kt += 32) {
        short8 af = *reinterpret_cast<const short8*>(aP + kt);
        short8 b0 = *reinterpret_cast<const short8*>(bqP + kt);
        short8 b1 = *reinterpret_cast<const short8*>(bkP + kt);
        short8 b2 = *reinterpret_cast<const short8*>(bvP + kt);
        acc[0] = __builtin_amdgcn_mfma_f32_16x16x32_bf16(af, b0, acc[0], 0, 0, 0);
        acc[1] = __builtin_amdgcn_mfma_f32_16x16x32_bf16(af, b1, acc[1], 0, 0, 0);
        acc[2] = __builtin_amdgcn_mfma_f32_16x16x32_bf16(af, b2, acc[2], 0, 0, 0);
    }

    // ---------- bias + RoPE + publish ----------
    // rows padded to 20 f32 (80B): 16B-aligned rows, conflict-light
    __shared__ float q_lds[64][20];
    __shared__ float k_lds[64][20];
    __shared__ float v_lds[64][20];

    const float bias_q = bq[gh * 16 + fr];
    const float bias_k = bk[gh * 16 + fr];
    const float bias_v = bv[gh * 16 + fr];
    const int   h = gh & 1;
    const int   f = fr >> 1;
    const float F0 = freqs[h * 8 + f];
    const float F1 = freqs[16 + h * 8 + f];
    const float F2 = freqs[32 + h * 8 + f];

    #pragma unroll
    for (int rr = 0; rr < 4; ++rr) {
        const int row  = w * 16 + hi * 4 + rr;       // local node row 0..63
        const int grow = gr * 64 + row;
        float qv = acc[0][rr] + bias_q;
        float kv = acc[1][rr] + bias_k;
        float vv = acc[2][rr] + bias_v;
        const float th = pos[grow * 3] * F0 + pos[grow * 3 + 1] * F1
                       + pos[grow * 3 + 2] * F2;
        const float cs = __cosf(th);
        const float sn = __sinf(th);
        const float qo = __shfl_xor(qv, 1, 64);
        const float ko = __shfl_xor(kv, 1, 64);
        qv = (fr & 1) ? (qo * sn + qv * cs) : (qv * cs - qo * sn);
        kv = (fr & 1) ? (ko * sn + kv * cs) : (kv * cs - ko * sn);
        q_lds[row][fr] = qv;
        k_lds[row][fr] = kv;
        v_lds[row][fr] = vv;
    }
    __syncthreads();

    // ---------- attention: lane = (qrow fr, k-quarter hi) ----------
    const int qrow = w * 16 + fr;
    f32x4 q0 = *reinterpret_cast<const f32x4*>(&q_lds[qrow][0]);
    f32x4 q1 = *reinterpret_cast<const f32x4*>(&q_lds[qrow][4]);
    f32x4 q2 = *reinterpret_cast<const f32x4*>(&q_lds[qrow][8]);
    f32x4 q3 = *reinterpret_cast<const f32x4*>(&q_lds[qrow][12]);

    float sc[16];
    #pragma unroll
    for (int j = 0; j < 16; ++j) {
        const float* kp = &k_lds[hi * 16 + j][0];
        f32x4 k0 = reinterpret_cast<const f32x4*>(kp)[0];
        f32x4 k1 = reinterpret_cast<const f32x4*>(kp)[1];
        f32x4 k2 = reinterpret_cast<const f32x4*>(kp)[2];
        f32x4 k3 = reinterpret_cast<const f32x4*>(kp)[3];
        float a = q0[0]*k0[0] + q0[1]*k0[1] + q0[2]*k0[2] + q0[3]*k0[3]
                + q1[0]*k1[0] + q1[1]*k1[1] + q1[2]*k1[2] + q1[3]*k1[3]
                + q2[0]*k2[0] + q2[1]*k2[1] + q2[2]*k2[2] + q2[3]*k2[3]
                + q3[0]*k3[0] + q3[1]*k3[1] + q3[2]*k3[2] + q3[3]*k3[3];
        sc[j] = a * 0.25f;
    }

    float mx = sc[0];
    #pragma unroll
    for (int j = 1; j < 16; ++j) mx = fmaxf(mx, sc[j]);
    mx = fmaxf(mx, __shfl_xor(mx, 16, 64));
    mx = fmaxf(mx, __shfl_xor(mx, 32, 64));

    float den = 0.f;
    #pragma unroll
    for (int j = 0; j < 16; ++j) {
        sc[j] = __expf(sc[j] - mx);
        den += sc[j];
    }
    den += __shfl_xor(den, 16, 64);
    den += __shfl_xor(den, 32, 64);

    float o[16];
    #pragma unroll
    for (int d = 0; d < 16; ++d) o[d] = 0.f;
    #pragma unroll
    for (int j = 0; j < 16; ++j) {
        const float p = sc[j];
        const float* vp = &v_lds[hi * 16 + j][0];
        f32x4 v0 = reinterpret_cast<const f32x4*>(vp)[0];
        f32x4 v1 = reinterpret_cast<const f32x4*>(vp)[1];
        f32x4 v2 = reinterpret_cast<const f32x4*>(vp)[2];
        f32x4 v3 = reinterpret_cast<const f32x4*>(vp)[3];
        #pragma unroll
        for (int d = 0; d < 4; ++d) {
            o[d]      += p * v0[d];
            o[4 + d]  += p * v1[d];
            o[8 + d]  += p * v2[d];
            o[12 + d] += p * v3[d];
        }
    }
    #pragma unroll
    for (int d = 0; d < 16; ++d) {
        o[d] += __shfl_xor(o[d], 16, 64);
        o[d] += __shfl_xor(o[d], 32, 64);
    }

    if (hi == 0) {
        const float inv = 1.0f / den;
        short8 r0, r1;
        #pragma unroll
        for (int d = 0; d < 8; ++d) {
            r0[d] = f2bf(o[d] * inv);
            r1[d] = f2bf(o[8 + d] * inv);
        }
        short* op = attn_out + (size_t)(gr * 64 + qrow) * KDIM + gh * 16;
        *reinterpret_cast<short8*>(op)     = r0;
        *reinterpret_cast<short8*>(op + 8) = r1;
    }
}

// ---- K2: out-projection, 1-wave blocks, 16x64 tile, no LDS/barriers -------
__global__ __launch_bounds__(64) void out_gemm_kernel(
    const short* __restrict__ A,     // attn bf16 [2048][384]
    const short* __restrict__ BT,    // WoT [384][384] bf16 (out cols as rows)
    const float* __restrict__ bias,
    float* __restrict__ C)           // [2048][384] f32
{
    const int r0   = blockIdx.x * 16;
    const int c0   = blockIdx.y * 64;
    const int lane = threadIdx.x;
    const int fr   = lane & 15;
    const int hi   = lane >> 4;

    const short* aP = A + (size_t)(r0 + fr) * KDIM + hi * 8;
    const short* b0P = BT + (size_t)(c0 + fr) * KDIM + hi * 8;
    const short* b1P = b0P + (size_t)16 * KDIM;
    const short* b2P = b1P + (size_t)16 * KDIM;
    const short* b3P = b2P + (size_t)16 * KDIM;

    f32x4 acc[4];
    acc[0] = (f32x4){0.f, 0.f, 0.f, 0.f};
    acc[1] = acc[0]; acc[2] = acc[0]; acc[3] = acc[0];

    #pragma unroll 4
    for (int kt = 0; kt < KDIM; kt += 32) {
        short8 af = *reinterpret_cast<const short8*>(aP + kt);
        short8 f0 = *reinterpret_cast<const short8*>(b0P + kt);
        short8 f1 = *reinterpret_cast<const short8*>(b1P + kt);
        short8 f2 = *reinterpret_cast<const short8*>(b2P + kt);
        short8 f3 = *reinterpret_cast<const short8*>(b3P + kt);
        acc[0] = __builtin_amdgcn_mfma_f32_16x16x32_bf16(af, f0, acc[0], 0, 0, 0);
        acc[1] = __builtin_amdgcn_mfma_f32_16x16x32_bf16(af, f1, acc[1], 0, 0, 0);
        acc[2] = __builtin_amdgcn_mfma_f32_16x16x32_bf16(af, f2, acc[2], 0, 0, 0);
        acc[3] = __builtin_amdgcn_mfma_f32_16x16x32_bf16(af, f3, acc[3], 0, 0, 0);
    }

    #pragma unroll
    for (int ct = 0; ct < 4; ++ct) {
        const int c  = c0 + ct * 16 + fr;
        const float bv = bias[c];
        const int rowb = r0 + hi * 4;
        #pragma unroll
        for (int rr = 0; rr < 4; ++rr)
            C[(size_t)(rowb + rr) * KDIM + c] = acc[ct][rr] + bv;
    }
}

extern "C" void kernel_launch(void* const* d_in, const int* in_sizes, int n_in,
                              void* d_out, int out_size, void* d_ws, size_t ws_size,
                              hipStream_t stream) {
    const float* x    = (const float*)d_in[0];
    const float* pos  = (const float*)d_in[1];
    const float* Wq   = (const float*)d_in[2];
    const float* bq   = (const float*)d_in[3];
    const float* Wk   = (const float*)d_in[4];
    const float* bk   = (const float*)d_in[5];
    const float* Wv   = (const float*)d_in[6];
    const float* bv   = (const float*)d_in[7];
    const float* Wo   = (const float*)d_in[8];
    const float* bo   = (const float*)d_in[9];
    const float* rope = (const float*)d_in[10];
    // d_in[11]=src, d_in[12]=dst: fixed fully-connected pattern, unused.

    char* ws = (char*)d_ws;
    short* WT   = (short*)(ws);              // 1536*384 bf16 = 1,179,648 B
    short* xb   = (short*)(ws + 1179648);    // 2048*384 bf16 = 1,572,864 B
    short* attn = (short*)(ws + 2752512);    // 2048*384 bf16 = 1,572,864 B

    prep_kernel<<<960, 256, 0, stream>>>(x, Wq, Wk, Wv, Wo, WT, xb);

    qkv_attn_kernel<<<NGRAPHS * GHEADS, 256, 0, stream>>>(
        xb, WT, bq, bk, bv, pos, rope, attn);

    {
        dim3 grid(NNODES / 16, KDIM / 64);
        out_gemm_kernel<<<grid, 64, 0, stream>>>(
            attn, WT + (size_t)1152 * KDIM, bo, (float*)d_out);
    }
}

// Round 4
// 109.507 us; speedup vs baseline: 1.0391x; 1.0391x over previous
//
#include <hip/hip_runtime.h>

// PlatonicConv: G=12, H_EFF=2, HEAD_D=16, GH=24, N=2048 (32 graphs x 64 nodes),
// IN_C=EMB=OUT_C=384. Fully-connected edges per graph => dense attention S=64,D=16
// per (graph, group-head). f32 in/out; bf16 MFMA inside.
//
// R4 pipeline (2 kernels):
//   KA fused: blocks 0..143 transpose Wo -> WoT bf16 (needed only by KB);
//             blocks 144.. : per (graph, gh): stage own W-slice f32->bf16 LDS,
//             QKV GEMM (A = f32 x direct, B = LDS), bias+RoPE, dense attention.
//   KB out-proj: 768 one-wave blocks, 16x64 tiles, direct-global frags.

#define NNODES   2048
#define KDIM     384
#define NGRAPHS  32
#define NPG      64
#define GHEADS   24
#define HDIM     16
#define WSROW    392      // padded LDS row (shorts): 196 words = 4 mod 8

typedef __attribute__((ext_vector_type(8))) short short8;
typedef __attribute__((ext_vector_type(4))) float f32x4;

__device__ __forceinline__ short f2bf(float f) {
    unsigned u = __builtin_bit_cast(unsigned, f);
    u += 0x7FFFu + ((u >> 16) & 1u);     // RTNE to bf16
    return (short)(u >> 16);
}

// ---- KA: fused {Wo transpose} | {W-slice prep + QKV GEMM + RoPE + attn} ----
__global__ __launch_bounds__(256) void fused_kernel(
    const float* __restrict__ x,      // [2048][384]
    const float* __restrict__ pos,    // [2048][3]
    const float* __restrict__ Wq, const float* __restrict__ bq,
    const float* __restrict__ Wk, const float* __restrict__ bk,
    const float* __restrict__ Wv, const float* __restrict__ bv,
    const float* __restrict__ Wo,
    const float* __restrict__ freqs,  // [3][2][8]
    short* __restrict__ WoT,          // [384][384] bf16 out
    short* __restrict__ attn_out)     // [2048][384] bf16 out
{
    __shared__ __align__(16) char smem[3 * 16 * WSROW * 2];   // 37632 B
    const int tid = threadIdx.x;

    if (blockIdx.x < 144) {
        // transpose one 32x32 tile of Wo: WoT[n][k] = Wo[k][n], f32->bf16
        float (*tile)[33] = reinterpret_cast<float(*)[33]>(smem);
        const int t  = blockIdx.x;
        const int k0 = (t / 12) * 32;
        const int n0 = (t % 12) * 32;
        const int cx = tid & 31;
        const int ty = tid >> 5;
        #pragma unroll
        for (int i = 0; i < 4; ++i) {
            const int rr = ty + 8 * i;
            tile[rr][cx] = Wo[(size_t)(k0 + rr) * KDIM + n0 + cx];
        }
        __syncthreads();
        #pragma unroll
        for (int i = 0; i < 4; ++i) {
            const int rr = ty + 8 * i;
            WoT[(size_t)(n0 + rr) * KDIM + k0 + cx] = f2bf(tile[cx][rr]);
        }
        return;
    }

    const int blk = blockIdx.x - 144;
    const int gr  = blk / GHEADS;
    const int gh  = blk - gr * GHEADS;

    // ---------- phase 0: stage this gh's weight slice into LDS (bf16) ------
    // WS[mat][c][k], rows padded to WSROW shorts.
    short* WS = reinterpret_cast<short*>(smem);
    for (int task = tid; task < 1152; task += 256) {
        const int mat = task / KDIM;          // 0=q 1=k 2=v
        const int k   = task - mat * KDIM;
        const float* W = (mat == 0) ? Wq : (mat == 1) ? Wk : Wv;
        const float* src = W + (size_t)k * KDIM + gh * 16;
        f32x4 w0 = reinterpret_cast<const f32x4*>(src)[0];
        f32x4 w1 = reinterpret_cast<const f32x4*>(src)[1];
        f32x4 w2 = reinterpret_cast<const f32x4*>(src)[2];
        f32x4 w3 = reinterpret_cast<const f32x4*>(src)[3];
        short* dst = WS + (size_t)mat * 16 * WSROW + k;
        #pragma unroll
        for (int c = 0; c < 4; ++c) {
            dst[(c)      * WSROW] = f2bf(w0[c]);
            dst[(c + 4)  * WSROW] = f2bf(w1[c]);
            dst[(c + 8)  * WSROW] = f2bf(w2[c]);
            dst[(c + 12) * WSROW] = f2bf(w3[c]);
        }
    }
    __syncthreads();

    // ---------- phase 1: QKV GEMM (16 rows/wave x 16 cols, K=384) ----------
    const int w    = tid >> 6;
    const int lane = tid & 63;
    const int fr   = lane & 15;
    const int hi   = lane >> 4;

    const float* aRow = x + (size_t)(gr * 64 + w * 16 + fr) * KDIM + hi * 8;
    const short* wsq = WS + (size_t)fr * WSROW + hi * 8;
    const short* wsk = wsq + (size_t)16 * WSROW;
    const short* wsv = wsk + (size_t)16 * WSROW;

    f32x4 acc[3];
    acc[0] = (f32x4){0.f, 0.f, 0.f, 0.f};
    acc[1] = acc[0];
    acc[2] = acc[0];

    #pragma unroll 4
    for (int kt = 0; kt < KDIM; kt += 32) {
        f32x4 a0 = *reinterpret_cast<const f32x4*>(aRow + kt);
        f32x4 a1 = *reinterpret_cast<const f32x4*>(aRow + kt + 4);
        short8 af;
        af[0] = f2bf(a0[0]); af[1] = f2bf(a0[1]); af[2] = f2bf(a0[2]); af[3] = f2bf(a0[3]);
        af[4] = f2bf(a1[0]); af[5] = f2bf(a1[1]); af[6] = f2bf(a1[2]); af[7] = f2bf(a1[3]);
        short8 b0 = *reinterpret_cast<const short8*>(wsq + kt);
        short8 b1 = *reinterpret_cast<const short8*>(wsk + kt);
        short8 b2 = *reinterpret_cast<const short8*>(wsv + kt);
        acc[0] = __builtin_amdgcn_mfma_f32_16x16x32_bf16(af, b0, acc[0], 0, 0, 0);
        acc[1] = __builtin_amdgcn_mfma_f32_16x16x32_bf16(af, b1, acc[1], 0, 0, 0);
        acc[2] = __builtin_amdgcn_mfma_f32_16x16x32_bf16(af, b2, acc[2], 0, 0, 0);
    }
    __syncthreads();   // all waves done reading WS; LDS is re-purposed below

    // ---------- phase 2: bias + RoPE, publish q/k/v to LDS ----------------
    float (*q_lds)[20] = reinterpret_cast<float(*)[20]>(smem);
    float (*k_lds)[20] = reinterpret_cast<float(*)[20]>(smem + 5120);
    float (*v_lds)[20] = reinterpret_cast<float(*)[20]>(smem + 10240);

    const float bias_q = bq[gh * 16 + fr];
    const float bias_k = bk[gh * 16 + fr];
    const float bias_v = bv[gh * 16 + fr];
    const int   h = gh & 1;
    const int   f = fr >> 1;
    const float F0 = freqs[h * 8 + f];
    const float F1 = freqs[16 + h * 8 + f];
    const float F2 = freqs[32 + h * 8 + f];

    #pragma unroll
    for (int rr = 0; rr < 4; ++rr) {
        const int row  = w * 16 + hi * 4 + rr;       // local node row 0..63
        const int grow = gr * 64 + row;
        float qv = acc[0][rr] + bias_q;
        float kv = acc[1][rr] + bias_k;
        float vv = acc[2][rr] + bias_v;
        const float th = pos[grow * 3] * F0 + pos[grow * 3 + 1] * F1
                       + pos[grow * 3 + 2] * F2;
        const float cs = __cosf(th);
        const float sn = __sinf(th);
        const float qo = __shfl_xor(qv, 1, 64);
        const float ko = __shfl_xor(kv, 1, 64);
        qv = (fr & 1) ? (qo * sn + qv * cs) : (qv * cs - qo * sn);
        kv = (fr & 1) ? (ko * sn + kv * cs) : (kv * cs - ko * sn);
        q_lds[row][fr] = qv;
        k_lds[row][fr] = kv;
        v_lds[row][fr] = vv;
    }
    __syncthreads();

    // ---------- phase 3: attention, lane = (qrow fr, k-quarter hi) ---------
    const int qrow = w * 16 + fr;
    f32x4 q0 = *reinterpret_cast<const f32x4*>(&q_lds[qrow][0]);
    f32x4 q1 = *reinterpret_cast<const f32x4*>(&q_lds[qrow][4]);
    f32x4 q2 = *reinterpret_cast<const f32x4*>(&q_lds[qrow][8]);
    f32x4 q3 = *reinterpret_cast<const f32x4*>(&q_lds[qrow][12]);

    float sc[16];
    #pragma unroll
    for (int j = 0; j < 16; ++j) {
        const float* kp = &k_lds[hi * 16 + j][0];
        f32x4 k0 = reinterpret_cast<const f32x4*>(kp)[0];
        f32x4 k1 = reinterpret_cast<const f32x4*>(kp)[1];
        f32x4 k2 = reinterpret_cast<const f32x4*>(kp)[2];
        f32x4 k3 = reinterpret_cast<const f32x4*>(kp)[3];
        float a = q0[0]*k0[0] + q0[1]*k0[1] + q0[2]*k0[2] + q0[3]*k0[3]
                + q1[0]*k1[0] + q1[1]*k1[1] + q1[2]*k1[2] + q1[3]*k1[3]
                + q2[0]*k2[0] + q2[1]*k2[1] + q2[2]*k2[2] + q2[3]*k2[3]
                + q3[0]*k3[0] + q3[1]*k3[1] + q3[2]*k3[2] + q3[3]*k3[3];
        sc[j] = a * 0.25f;
    }

    float mx = sc[0];
    #pragma unroll
    for (int j = 1; j < 16; ++j) mx = fmaxf(mx, sc[j]);
    mx = fmaxf(mx, __shfl_xor(mx, 16, 64));
    mx = fmaxf(mx, __shfl_xor(mx, 32, 64));

    float den = 0.f;
    #pragma unroll
    for (int j = 0; j < 16; ++j) {
        sc[j] = __expf(sc[j] - mx);
        den += sc[j];
    }
    den += __shfl_xor(den, 16, 64);
    den += __shfl_xor(den, 32, 64);

    float o[16];
    #pragma unroll
    for (int d = 0; d < 16; ++d) o[d] = 0.f;
    #pragma unroll
    for (int j = 0; j < 16; ++j) {
        const float p = sc[j];
        const float* vp = &v_lds[hi * 16 + j][0];
        f32x4 v0 = reinterpret_cast<const f32x4*>(vp)[0];
        f32x4 v1 = reinterpret_cast<const f32x4*>(vp)[1];
        f32x4 v2 = reinterpret_cast<const f32x4*>(vp)[2];
        f32x4 v3 = reinterpret_cast<const f32x4*>(vp)[3];
        #pragma unroll
        for (int d = 0; d < 4; ++d) {
            o[d]      += p * v0[d];
            o[4 + d]  += p * v1[d];
            o[8 + d]  += p * v2[d];
            o[12 + d] += p * v3[d];
        }
    }
    #pragma unroll
    for (int d = 0; d < 16; ++d) {
        o[d] += __shfl_xor(o[d], 16, 64);
        o[d] += __shfl_xor(o[d], 32, 64);
    }

    if (hi == 0) {
        const float inv = 1.0f / den;
        short8 r0, r1;
        #pragma unroll
        for (int d = 0; d < 8; ++d) {
            r0[d] = f2bf(o[d] * inv);
            r1[d] = f2bf(o[8 + d] * inv);
        }
        short* op = attn_out + (size_t)(gr * 64 + qrow) * KDIM + gh * 16;
        *reinterpret_cast<short8*>(op)     = r0;
        *reinterpret_cast<short8*>(op + 8) = r1;
    }
}

// ---- KB: out-projection, 1-wave blocks, 16x64 tile, no LDS/barriers -------
__global__ __launch_bounds__(64) void out_gemm_kernel(
    const short* __restrict__ A,     // attn bf16 [2048][384]
    const short* __restrict__ BT,    // WoT [384][384] bf16 (out cols as rows)
    const float* __restrict__ bias,
    float* __restrict__ C)           // [2048][384] f32
{
    const int r0   = blockIdx.x * 16;
    const int c0   = blockIdx.y * 64;
    const int lane = threadIdx.x;
    const int fr   = lane & 15;
    const int hi   = lane >> 4;

    const short* aP  = A + (size_t)(r0 + fr) * KDIM + hi * 8;
    const short* b0P = BT + (size_t)(c0 + fr) * KDIM + hi * 8;
    const short* b1P = b0P + (size_t)16 * KDIM;
    const short* b2P = b1P + (size_t)16 * KDIM;
    const short* b3P = b2P + (size_t)16 * KDIM;

    f32x4 acc[4];
    acc[0] = (f32x4){0.f, 0.f, 0.f, 0.f};
    acc[1] = acc[0]; acc[2] = acc[0]; acc[3] = acc[0];

    #pragma unroll 4
    for (int kt = 0; kt < KDIM; kt += 32) {
        short8 af = *reinterpret_cast<const short8*>(aP + kt);
        short8 f0 = *reinterpret_cast<const short8*>(b0P + kt);
        short8 f1 = *reinterpret_cast<const short8*>(b1P + kt);
        short8 f2 = *reinterpret_cast<const short8*>(b2P + kt);
        short8 f3 = *reinterpret_cast<const short8*>(b3P + kt);
        acc[0] = __builtin_amdgcn_mfma_f32_16x16x32_bf16(af, f0, acc[0], 0, 0, 0);
        acc[1] = __builtin_amdgcn_mfma_f32_16x16x32_bf16(af, f1, acc[1], 0, 0, 0);
        acc[2] = __builtin_amdgcn_mfma_f32_16x16x32_bf16(af, f2, acc[2], 0, 0, 0);
        acc[3] = __builtin_amdgcn_mfma_f32_16x16x32_bf16(af, f3, acc[3], 0, 0, 0);
    }

    #pragma unroll
    for (int ct = 0; ct < 4; ++ct) {
        const int c    = c0 + ct * 16 + fr;
        const float bv = bias[c];
        const int rowb = r0 + hi * 4;
        #pragma unroll
        for (int rr = 0; rr < 4; ++rr)
            C[(size_t)(rowb + rr) * KDIM + c] = acc[ct][rr] + bv;
    }
}

extern "C" void kernel_launch(void* const* d_in, const int* in_sizes, int n_in,
                              void* d_out, int out_size, void* d_ws, size_t ws_size,
                              hipStream_t stream) {
    const float* x    = (const float*)d_in[0];
    const float* pos  = (const float*)d_in[1];
    const float* Wq   = (const float*)d_in[2];
    const float* bq   = (const float*)d_in[3];
    const float* Wk   = (const float*)d_in[4];
    const float* bk   = (const float*)d_in[5];
    const float* Wv   = (const float*)d_in[6];
    const float* bv   = (const float*)d_in[7];
    const float* Wo   = (const float*)d_in[8];
    const float* bo   = (const float*)d_in[9];
    const float* rope = (const float*)d_in[10];
    // d_in[11]=src, d_in[12]=dst: fixed fully-connected pattern, unused.

    char* ws = (char*)d_ws;
    short* WoT  = (short*)(ws);            // 384*384 bf16 = 294,912 B
    short* attn = (short*)(ws + 294912);   // 2048*384 bf16 = 1,572,864 B

    fused_kernel<<<144 + NGRAPHS * GHEADS, 256, 0, stream>>>(
        x, pos, Wq, bq, Wk, bk, Wv, bv, Wo, rope, WoT, attn);

    {
        dim3 grid(NNODES / 16, KDIM / 64);
        out_gemm_kernel<<<grid, 64, 0, stream>>>(attn, WoT, bo, (float*)d_out);
    }
}